// Round 1
// baseline (325.769 us; speedup 1.0000x reference)
//
#include <hip/hip_runtime.h>

typedef __bf16 bf16_t;
typedef __bf16 bf16x8 __attribute__((ext_vector_type(8)));
typedef __bf16 bf16x4 __attribute__((ext_vector_type(4)));
typedef float  f32x4  __attribute__((ext_vector_type(4)));

#define PIX 196      // 14*14
#define P_  12544    // 16*28*28
#define M_  512

// ---------------- conv_w [c][d][2][2] -> wtq[q][c][d] (fp32) ----------------
__global__ __launch_bounds__(256) void k_wtq(const float* __restrict__ conv_w,
                                             float* __restrict__ wtq) {
  int c = blockIdx.x, d = threadIdx.x;
  f32x4 w = *reinterpret_cast<const f32x4*>(conv_w + (c * 256 + d) * 4);
#pragma unroll
  for (int q = 0; q < 4; ++q) wtq[(q * 256 + c) * 256 + d] = w[q];
}

// ---------------- ny -> bf16 + e_n[c,m] = exp(-||ny||^2/(2s^2))*alpha ----------------
__global__ __launch_bounds__(256) void k_nyprep(const float* __restrict__ ny,
                                                const float* __restrict__ alpha,
                                                const float* __restrict__ sigma,
                                                bf16_t* __restrict__ nyb,
                                                float* __restrict__ e_n) {
  int lane = threadIdx.x & 63;
  int row = blockIdx.x * 4 + (threadIdx.x >> 6);   // c*512+m, < 10240
  f32x4 v = *reinterpret_cast<const f32x4*>(ny + row * 256 + lane * 4);
  bf16x4 h;
  float sq = 0.f;
#pragma unroll
  for (int i = 0; i < 4; ++i) {
    h[i] = (bf16_t)v[i];
    float fv = (float)h[i];
    sq += fv * fv;
  }
  *reinterpret_cast<bf16x4*>(nyb + row * 256 + lane * 4) = h;
#pragma unroll
  for (int o = 1; o < 64; o <<= 1) sq += __shfl_xor(sq, o);
  if (lane == 0) {
    float s = sigma[0];
    e_n[row] = __expf(-sq / (2.f * s * s)) * alpha[row];
  }
}

// ---------------- ConvTranspose + ReLU + normalize -> f_bf16[p][d] ----------------
// block: 1024 threads = (q, d); handles 16 input pixels; fp32 accumulation.
__global__ __launch_bounds__(1024) void k_conv(const float* __restrict__ x,
                                               const float* __restrict__ wtq,
                                               const float* __restrict__ conv_b,
                                               const float* __restrict__ mean,
                                               const float* __restrict__ mean_norm,
                                               bf16_t* __restrict__ fb) {
  __shared__ float xs[16][257];
  int t = threadIdx.x;
  int p3base = blockIdx.x * 16;
#pragma unroll
  for (int r = 0; r < 4; ++r) {
    int idx = r * 1024 + t;
    int cc = idx >> 4, pp = idx & 15;
    int p3 = p3base + pp;
    int n = p3 / PIX, hw = p3 % PIX;
    xs[pp][cc] = x[(n * 256 + cc) * PIX + hw];
  }
  __syncthreads();
  int q = t >> 8, d = t & 255;
  float bias = conv_b[d];
  float acc[16];
#pragma unroll
  for (int pp = 0; pp < 16; ++pp) acc[pp] = bias;
  const float* wq = wtq + q * 65536 + d;
#pragma unroll 4
  for (int c = 0; c < 256; ++c) {
    float wv = wq[c * 256];
#pragma unroll
    for (int pp = 0; pp < 16; ++pp) acc[pp] += xs[pp][c] * wv;
  }
  float mn = mean[d];
  float scale = 20.f / mean_norm[0];
  int i2 = q >> 1, j2 = q & 1;
#pragma unroll
  for (int pp = 0; pp < 16; ++pp) {
    int p3 = p3base + pp;
    int n = p3 / PIX, hw = p3 % PIX;
    int h = hw / 14, w = hw % 14;
    int p = n * 784 + (2 * h + i2) * 28 + (2 * w + j2);
    float v = fmaxf(acc[pp], 0.f);
    v = (v - mn) * scale;
    fb[p * 256 + d] = (bf16_t)v;
  }
}

// ---------------- e_f[p] = exp(-||f_p||^2/(2s^2)) from rounded bf16 ----------------
__global__ __launch_bounds__(256) void k_ef(const bf16_t* __restrict__ fb,
                                            const float* __restrict__ sigma,
                                            float* __restrict__ e_f) {
  int lane = threadIdx.x & 63;
  int row = blockIdx.x * 4 + (threadIdx.x >> 6);   // < 12544
  bf16x4 h = *reinterpret_cast<const bf16x4*>(fb + row * 256 + lane * 4);
  float sq = 0.f;
#pragma unroll
  for (int i = 0; i < 4; ++i) {
    float fv = (float)h[i];
    sq += fv * fv;
  }
#pragma unroll
  for (int o = 1; o < 64; o <<= 1) sq += __shfl_xor(sq, o);
  if (lane == 0) {
    float s = sigma[0];
    e_f[row] = __expf(-sq / (2.f * s * s));
  }
}

// ---------------- background channel = -2 ----------------
__global__ __launch_bounds__(256) void k_fill(float* __restrict__ out) {
  int idx = blockIdx.x * 256 + threadIdx.x;   // < 12544
  int n = idx / 784, pix = idx % 784;
  out[n * 16464 + pix] = -2.0f;
}

// ---------------- main: scores[c,p] = e_f[p] * sum_m e_n[m] * exp(dot/s^2) ----------------
// grid (98, 20); 4 waves; wave owns 32 p-rows (2 row-frags); m-loop 16 wide, double-buffered.
__global__ __launch_bounds__(256) void k_falkon(const bf16_t* __restrict__ fb,
                                                const float* __restrict__ e_f,
                                                const bf16_t* __restrict__ nyb,
                                                const float* __restrict__ e_n,
                                                const float* __restrict__ sigma,
                                                float* __restrict__ out) {
  int c = blockIdx.y;
  int pb = blockIdx.x * 128;
  int tid = threadIdx.x;
  int wv = tid >> 6, lane = tid & 63;
  int lg = lane >> 4, lc = lane & 15;
  const bf16_t* nyc = nyb + c * (M_ * 256);
  const float* enc = e_n + c * M_;

  // A fragments: rows pb + wv*32 + r*16 + lc, k = lg*8 + ks*32 + j
  bf16x8 a[2][8];
#pragma unroll
  for (int r = 0; r < 2; ++r) {
    int row = pb + wv * 32 + r * 16 + lc;
    const bf16_t* ap = fb + row * 256 + lg * 8;
#pragma unroll
    for (int ks = 0; ks < 8; ++ks)
      a[r][ks] = *reinterpret_cast<const bf16x8*>(ap + ks * 32);
  }

  float s = sigma[0];
  float kk = 1.f / (s * s);

  float sacc[2][4];
#pragma unroll
  for (int r = 0; r < 2; ++r)
#pragma unroll
    for (int j = 0; j < 4; ++j) sacc[r][j] = 0.f;

  bf16x8 bufA[8], bufB[8];
  const bf16_t* bbase = nyc + lc * 256 + lg * 8;

  auto loadB = [&](bf16x8* buf, int mb) {
    const bf16_t* bp = bbase + mb * 256;
#pragma unroll
    for (int ks = 0; ks < 8; ++ks)
      buf[ks] = *reinterpret_cast<const bf16x8*>(bp + ks * 32);
  };
  auto compute = [&](const bf16x8* buf, int mb) {
    f32x4 acc0 = {0.f, 0.f, 0.f, 0.f}, acc1 = {0.f, 0.f, 0.f, 0.f};
#pragma unroll
    for (int ks = 0; ks < 8; ++ks) {
      acc0 = __builtin_amdgcn_mfma_f32_16x16x32_bf16(a[0][ks], buf[ks], acc0, 0, 0, 0);
      acc1 = __builtin_amdgcn_mfma_f32_16x16x32_bf16(a[1][ks], buf[ks], acc1, 0, 0, 0);
    }
    float en = enc[mb + lc];
#pragma unroll
    for (int j = 0; j < 4; ++j) {
      sacc[0][j] += en * __expf(acc0[j] * kk);
      sacc[1][j] += en * __expf(acc1[j] * kk);
    }
  };

  loadB(bufA, 0);
  for (int mb = 0; mb < 512; mb += 32) {
    loadB(bufB, mb + 16);
    compute(bufA, mb);
    if (mb + 32 < 512) loadB(bufA, mb + 32);
    compute(bufB, mb + 16);
  }

  // reduce over the 16 m-columns (lanes sharing lg), then write
#pragma unroll
  for (int r = 0; r < 2; ++r) {
#pragma unroll
    for (int j = 0; j < 4; ++j) {
      float v = sacc[r][j];
      v += __shfl_xor(v, 1);
      v += __shfl_xor(v, 2);
      v += __shfl_xor(v, 4);
      v += __shfl_xor(v, 8);
      if (lc == 0) {
        int p = pb + wv * 32 + r * 16 + lg * 4 + j;
        float score = v * e_f[p];
        int n = p / 784, pix = p % 784;
        out[n * 16464 + (c + 1) * 784 + pix] = score;
      }
    }
  }
}

extern "C" void kernel_launch(void* const* d_in, const int* in_sizes, int n_in,
                              void* d_out, int out_size, void* d_ws, size_t ws_size,
                              hipStream_t stream) {
  const float* x         = (const float*)d_in[0];
  const float* conv_w    = (const float*)d_in[1];
  const float* conv_b    = (const float*)d_in[2];
  const float* mean      = (const float*)d_in[3];
  const float* mean_norm = (const float*)d_in[4];
  const float* ny        = (const float*)d_in[5];
  const float* alpha     = (const float*)d_in[6];
  const float* sigma     = (const float*)d_in[7];
  float* out = (float*)d_out;

  char* ws = (char*)d_ws;
  float*  wtq = (float*)ws;                    // 1,048,576 B
  bf16_t* fb  = (bf16_t*)(ws + 1048576);       // 6,422,528 B
  float*  e_f = (float*)(ws + 7471104);        //    50,176 B
  bf16_t* nyb = (bf16_t*)(ws + 7521280);       // 5,242,880 B
  float*  e_n = (float*)(ws + 12764160);       //    40,960 B

  k_wtq<<<dim3(256), dim3(256), 0, stream>>>(conv_w, wtq);
  k_nyprep<<<dim3(2560), dim3(256), 0, stream>>>(ny, alpha, sigma, nyb, e_n);
  k_conv<<<dim3(196), dim3(1024), 0, stream>>>(x, wtq, conv_b, mean, mean_norm, fb);
  k_ef<<<dim3(3136), dim3(256), 0, stream>>>(fb, sigma, e_f);
  k_fill<<<dim3(49), dim3(256), 0, stream>>>(out);
  k_falkon<<<dim3(98, 20), dim3(256), 0, stream>>>(fb, e_f, nyb, e_n, sigma, out);
}

// Round 2
// 166.918 us; speedup vs baseline: 1.9517x; 1.9517x over previous
//
#include <hip/hip_runtime.h>

typedef __bf16 bf16_t;
typedef __bf16 bf16x8 __attribute__((ext_vector_type(8)));
typedef __bf16 bf16x4 __attribute__((ext_vector_type(4)));
typedef float  f32x4  __attribute__((ext_vector_type(4)));

#define PIX 196      // 14*14
#define P_  12544    // 16*28*28
#define M_  512

// ---------------- conv_w [c][d][2][2] -> wtq[q][c][d] (fp32) ----------------
__global__ __launch_bounds__(256) void k_wtq(const float* __restrict__ conv_w,
                                             float* __restrict__ wtq) {
  int c = blockIdx.x, d = threadIdx.x;
  f32x4 w = *reinterpret_cast<const f32x4*>(conv_w + (c * 256 + d) * 4);
#pragma unroll
  for (int q = 0; q < 4; ++q) wtq[(q * 256 + c) * 256 + d] = w[q];
}

// ---------------- ny -> fragment-native bf16 + e_n = exp(-||ny||^2/2s^2)*alpha ----
// Swizzled layout: element (c, m, k) with t=m>>4, mr=m&15, ks=k>>5, lg=(k>>3)&3, j=k&7
//   -> nys[(c*32+t)*4096 + ks*512 + (lg*16+mr)*8 + j]
// so k_falkon's loadB is:  buf[ks] = 16B @ (c*32+t)*4096 + ks*512 + lane*8  (coalesced 1KB)
__global__ __launch_bounds__(256) void k_nyprep(const float* __restrict__ ny,
                                                const float* __restrict__ alpha,
                                                const float* __restrict__ sigma,
                                                bf16_t* __restrict__ nys,
                                                float* __restrict__ e_n) {
  int l = threadIdx.x & 63;
  int row = blockIdx.x * 4 + (threadIdx.x >> 6);   // c*512+m, < 10240
  int c = row >> 9, m = row & 511;
  int t = m >> 4, mr = m & 15;
  f32x4 v = *reinterpret_cast<const f32x4*>(ny + row * 256 + l * 4);
  bf16x4 h;
  float sq = 0.f;
#pragma unroll
  for (int i = 0; i < 4; ++i) {
    h[i] = (bf16_t)v[i];
    float fv = (float)h[i];
    sq += fv * fv;
  }
  int ks = l >> 3, lg = (l >> 1) & 3, j0 = (l & 1) * 4;
  *reinterpret_cast<bf16x4*>(nys + (c * 32 + t) * 4096 + ks * 512 + (lg * 16 + mr) * 8 + j0) = h;
#pragma unroll
  for (int o = 1; o < 64; o <<= 1) sq += __shfl_xor(sq, o);
  if (l == 0) {
    float s = sigma[0];
    e_n[row] = __expf(-sq / (2.f * s * s)) * alpha[row];
  }
}

// ---------------- ConvTranspose + ReLU + normalize -> f_bf16[p][d] ----------------
__global__ __launch_bounds__(1024) void k_conv(const float* __restrict__ x,
                                               const float* __restrict__ wtq,
                                               const float* __restrict__ conv_b,
                                               const float* __restrict__ mean,
                                               const float* __restrict__ mean_norm,
                                               bf16_t* __restrict__ fb) {
  __shared__ float xs[16][257];
  int t = threadIdx.x;
  int p3base = blockIdx.x * 16;
#pragma unroll
  for (int r = 0; r < 4; ++r) {
    int idx = r * 1024 + t;
    int cc = idx >> 4, pp = idx & 15;
    int p3 = p3base + pp;
    int n = p3 / PIX, hw = p3 % PIX;
    xs[pp][cc] = x[(n * 256 + cc) * PIX + hw];
  }
  __syncthreads();
  int q = t >> 8, d = t & 255;
  float bias = conv_b[d];
  float acc[16];
#pragma unroll
  for (int pp = 0; pp < 16; ++pp) acc[pp] = bias;
  const float* wq = wtq + q * 65536 + d;
#pragma unroll 4
  for (int c = 0; c < 256; ++c) {
    float wv = wq[c * 256];
#pragma unroll
    for (int pp = 0; pp < 16; ++pp) acc[pp] += xs[pp][c] * wv;
  }
  float mn = mean[d];
  float scale = 20.f / mean_norm[0];
  int i2 = q >> 1, j2 = q & 1;
#pragma unroll
  for (int pp = 0; pp < 16; ++pp) {
    int p3 = p3base + pp;
    int n = p3 / PIX, hw = p3 % PIX;
    int h = hw / 14, w = hw % 14;
    int p = n * 784 + (2 * h + i2) * 28 + (2 * w + j2);
    float v = fmaxf(acc[pp], 0.f);
    v = (v - mn) * scale;
    fb[p * 256 + d] = (bf16_t)v;
  }
}

// ---------------- e_f[p] = exp(-||f_p||^2/(2s^2)) from rounded bf16 ----------------
__global__ __launch_bounds__(256) void k_ef(const bf16_t* __restrict__ fb,
                                            const float* __restrict__ sigma,
                                            float* __restrict__ e_f) {
  int lane = threadIdx.x & 63;
  int row = blockIdx.x * 4 + (threadIdx.x >> 6);   // < 12544
  bf16x4 h = *reinterpret_cast<const bf16x4*>(fb + row * 256 + lane * 4);
  float sq = 0.f;
#pragma unroll
  for (int i = 0; i < 4; ++i) {
    float fv = (float)h[i];
    sq += fv * fv;
  }
#pragma unroll
  for (int o = 1; o < 64; o <<= 1) sq += __shfl_xor(sq, o);
  if (lane == 0) {
    float s = sigma[0];
    e_f[row] = __expf(-sq / (2.f * s * s));
  }
}

// ---------------- background channel = -2 ----------------
__global__ __launch_bounds__(256) void k_fill(float* __restrict__ out) {
  int idx = blockIdx.x * 256 + threadIdx.x;   // < 12544
  int n = idx / 784, pix = idx % 784;
  out[n * 16464 + pix] = -2.0f;
}

// ---------------- main: scores[c,p] = e_f[p] * sum_m e_n[m] * exp(dot/s^2) ----------
// grid (98, 20); 4 waves; wave owns 32 p-rows; m-loop 16-wide chunks, double-buffered
// register loads from the pre-swizzled nys (coalesced); e_n read from LDS (lgkmcnt,
// keeps the vmcnt prefetch queue intact).
__global__ __launch_bounds__(256) void k_falkon(const bf16_t* __restrict__ fb,
                                                const float* __restrict__ e_f,
                                                const bf16_t* __restrict__ nys,
                                                const float* __restrict__ e_n,
                                                const float* __restrict__ sigma,
                                                float* __restrict__ out) {
  __shared__ float lds_en[512];
  int c = blockIdx.y;
  int pb = blockIdx.x * 128;
  int tid = threadIdx.x;
  int wv = tid >> 6, lane = tid & 63;
  int lg = lane >> 4, lc = lane & 15;

  lds_en[tid] = e_n[c * M_ + tid];
  lds_en[tid + 256] = e_n[c * M_ + tid + 256];

  // A fragments: rows pb + wv*32 + r*16 + lc, k = lg*8 + ks*32 + j
  bf16x8 a[2][8];
#pragma unroll
  for (int r = 0; r < 2; ++r) {
    int row = pb + wv * 32 + r * 16 + lc;
    const bf16_t* ap = fb + row * 256 + lg * 8;
#pragma unroll
    for (int ks = 0; ks < 8; ++ks)
      a[r][ks] = *reinterpret_cast<const bf16x8*>(ap + ks * 32);
  }

  float s = sigma[0];
  float kk = 1.f / (s * s);

  float sacc[2][4];
#pragma unroll
  for (int r = 0; r < 2; ++r)
#pragma unroll
    for (int j = 0; j < 4; ++j) sacc[r][j] = 0.f;

  bf16x8 bufA[8], bufB[8];
  const bf16_t* bbase = nys + c * (M_ * 256) + lane * 8;

  auto loadB = [&](bf16x8* buf, int t) {
    const bf16_t* bp = bbase + t * 4096;
#pragma unroll
    for (int ks = 0; ks < 8; ++ks)
      buf[ks] = *reinterpret_cast<const bf16x8*>(bp + ks * 512);
  };
  auto compute = [&](const bf16x8* buf, int t) {
    float en = lds_en[t * 16 + lc];
    f32x4 acc0 = {0.f, 0.f, 0.f, 0.f}, acc1 = {0.f, 0.f, 0.f, 0.f};
#pragma unroll
    for (int ks = 0; ks < 8; ++ks) {
      acc0 = __builtin_amdgcn_mfma_f32_16x16x32_bf16(a[0][ks], buf[ks], acc0, 0, 0, 0);
      acc1 = __builtin_amdgcn_mfma_f32_16x16x32_bf16(a[1][ks], buf[ks], acc1, 0, 0, 0);
    }
#pragma unroll
    for (int j = 0; j < 4; ++j) {
      sacc[0][j] += en * __expf(acc0[j] * kk);
      sacc[1][j] += en * __expf(acc1[j] * kk);
    }
  };

  __syncthreads();   // lds_en ready

  loadB(bufA, 0);
  for (int t = 0; t < 32; t += 2) {
    loadB(bufB, t + 1);
    compute(bufA, t);
    if (t + 2 < 32) loadB(bufA, t + 2);
    compute(bufB, t + 1);
  }

  // reduce over the 16 m-columns (lanes sharing lg), then write
#pragma unroll
  for (int r = 0; r < 2; ++r) {
#pragma unroll
    for (int j = 0; j < 4; ++j) {
      float v = sacc[r][j];
      v += __shfl_xor(v, 1);
      v += __shfl_xor(v, 2);
      v += __shfl_xor(v, 4);
      v += __shfl_xor(v, 8);
      if (lc == 0) {
        int p = pb + wv * 32 + r * 16 + lg * 4 + j;
        float score = v * e_f[p];
        int n = p / 784, pix = p % 784;
        out[n * 16464 + (c + 1) * 784 + pix] = score;
      }
    }
  }
}

extern "C" void kernel_launch(void* const* d_in, const int* in_sizes, int n_in,
                              void* d_out, int out_size, void* d_ws, size_t ws_size,
                              hipStream_t stream) {
  const float* x         = (const float*)d_in[0];
  const float* conv_w    = (const float*)d_in[1];
  const float* conv_b    = (const float*)d_in[2];
  const float* mean      = (const float*)d_in[3];
  const float* mean_norm = (const float*)d_in[4];
  const float* ny        = (const float*)d_in[5];
  const float* alpha     = (const float*)d_in[6];
  const float* sigma     = (const float*)d_in[7];
  float* out = (float*)d_out;

  char* ws = (char*)d_ws;
  float*  wtq = (float*)ws;                    // 1,048,576 B
  bf16_t* fb  = (bf16_t*)(ws + 1048576);       // 6,422,528 B
  float*  e_f = (float*)(ws + 7471104);        //    50,176 B
  bf16_t* nys = (bf16_t*)(ws + 7521280);       // 5,242,880 B
  float*  e_n = (float*)(ws + 12764160);       //    40,960 B

  k_wtq<<<dim3(256), dim3(256), 0, stream>>>(conv_w, wtq);
  k_nyprep<<<dim3(2560), dim3(256), 0, stream>>>(ny, alpha, sigma, nys, e_n);
  k_conv<<<dim3(196), dim3(1024), 0, stream>>>(x, wtq, conv_b, mean, mean_norm, fb);
  k_ef<<<dim3(3136), dim3(256), 0, stream>>>(fb, sigma, e_f);
  k_fill<<<dim3(49), dim3(256), 0, stream>>>(out);
  k_falkon<<<dim3(98, 20), dim3(256), 0, stream>>>(fb, e_f, nys, e_n, sigma, out);
}

// Round 3
// 123.229 us; speedup vs baseline: 2.6436x; 1.3545x over previous
//
#include <hip/hip_runtime.h>

typedef __bf16 bf16_t;
typedef __bf16 bf16x8 __attribute__((ext_vector_type(8)));
typedef __bf16 bf16x4 __attribute__((ext_vector_type(4)));
typedef float  f32x4  __attribute__((ext_vector_type(4)));
typedef float  f32x16 __attribute__((ext_vector_type(16)));

#define PIX 196      // 14*14
#define P_  12544    // 16*28*28
#define M_  512

__device__ inline void gload_lds16(const void* g, void* l) {
  __builtin_amdgcn_global_load_lds((const __attribute__((address_space(1))) void*)g,
                                   (__attribute__((address_space(3))) void*)l,
                                   16, 0, 0);
}

// ---- conv_w [c][d][2][2] fp32 -> wtb bf16, fragment-native:
// element (k=c, col=q*256+d) -> wtb[((cf*16+ks)*64 + lfrag)*8 + j]
//   cf=col>>5, ks=c>>4, lfrag=((c>>3)&1)*32 + (col&31), j=c&7
__global__ __launch_bounds__(256) void k_wtb(const float* __restrict__ conv_w,
                                             bf16_t* __restrict__ wtb) {
  int c = blockIdx.x, d = threadIdx.x;
  f32x4 w = *reinterpret_cast<const f32x4*>(conv_w + (c * 256 + d) * 4);
  int ks = c >> 4, kb = (c >> 3) & 1, j = c & 7;
#pragma unroll
  for (int q = 0; q < 4; ++q) {
    int col = q * 256 + d;
    int cf = col >> 5;
    int lfrag = kb * 32 + (col & 31);
    wtb[((cf * 16 + ks) * 64 + lfrag) * 8 + j] = (bf16_t)w[q];
  }
}

// ---- x[n][c][hw] fp32 -> xb[p3=n*196+hw][c] bf16 (transpose via LDS) ----
__global__ __launch_bounds__(256) void k_xt(const float* __restrict__ x,
                                            bf16_t* __restrict__ xb) {
  __shared__ float xs[64][198];
  int n = blockIdx.x, c0 = blockIdx.y * 64;
  int t = threadIdx.x;
  const float* xp = x + (n * 256 + c0) * PIX;
#pragma unroll 7
  for (int r = 0; r < 49; ++r) {           // 64*196 = 12544 = 49*256
    int idx = r * 256 + t;
    xs[idx / PIX][idx % PIX] = xp[idx];
  }
  __syncthreads();
  for (int r = 0; r < 13; ++r) {           // 196*16 = 3136 slots
    int idx = r * 256 + t;
    if (idx < 3136) {
      int hw = idx >> 4, c4 = idx & 15;
      bf16x4 h;
#pragma unroll
      for (int i = 0; i < 4; ++i) h[i] = (bf16_t)xs[c4 * 4 + i][hw];
      *reinterpret_cast<bf16x4*>(xb + (n * PIX + hw) * 256 + c0 + c4 * 4) = h;
    }
  }
}

// ---- ny -> fragment/LDS-native bf16 chunks + e_n = exp(-||ny||^2/2s^2)*alpha ----
// element (c,m,k): t=m>>5, ks=k>>4, lfrag=((k>>3)&1)*32+(m&31), j=k&7
//   -> nys[((c*16+t)*16 + ks)*512 + lfrag*8 + j]   (chunk = 16 KB, LDS image)
__global__ __launch_bounds__(256) void k_nyprep(const float* __restrict__ ny,
                                                const float* __restrict__ alpha,
                                                const float* __restrict__ sigma,
                                                bf16_t* __restrict__ nys,
                                                float* __restrict__ e_n) {
  int l = threadIdx.x & 63;
  int row = blockIdx.x * 4 + (threadIdx.x >> 6);   // c*512+m, < 10240
  int c = row >> 9, m = row & 511;
  f32x4 v = *reinterpret_cast<const f32x4*>(ny + row * 256 + l * 4);
  bf16x4 h;
  float sq = 0.f;
#pragma unroll
  for (int i = 0; i < 4; ++i) {
    h[i] = (bf16_t)v[i];
    float fv = (float)h[i];
    sq += fv * fv;
  }
  int t = m >> 5, mr = m & 31;
  int ks = l >> 2, kb = (l >> 1) & 1, j0 = (l & 1) * 4;
  *reinterpret_cast<bf16x4*>(nys + ((c * 16 + t) * 16 + ks) * 512 + (kb * 32 + mr) * 8 + j0) = h;
#pragma unroll
  for (int o = 1; o < 64; o <<= 1) sq += __shfl_xor(sq, o);
  if (l == 0) {
    float s = sigma[0];
    e_n[row] = __expf(-sq / (2.f * s * s)) * alpha[row];
  }
}

// ---- conv as GEMM: fb[p][d] = bf16(((relu(xb·wtb + b)) - mean) * scale) ----
// grid (49, 8); block 64 p3-rows x 128 cols; 4 waves (wr,wc), 32x32x16 MFMA.
__global__ __launch_bounds__(256) void k_convT(const bf16_t* __restrict__ xb,
                                               const bf16_t* __restrict__ wtb,
                                               const float* __restrict__ conv_b,
                                               const float* __restrict__ mean,
                                               const float* __restrict__ mean_norm,
                                               bf16_t* __restrict__ fb) {
  __shared__ bf16_t bs[32768];   // 64 KB: 4 col-frags x 16 ks x 64 lanes x 8
  int rb = blockIdx.x * 64, cbase = blockIdx.y * 128;
  int tid = threadIdx.x, w = tid >> 6, l = tid & 63;
  int wr = w >> 1, wc = w & 1;
  const bf16_t* bsrc = wtb + blockIdx.y * 32768;
#pragma unroll
  for (int r = 0; r < 16; ++r) {
    int s = (r * 4 + w) * 64 + l;          // < 4096 slots of 16B
    gload_lds16(bsrc + s * 8, bs + s * 8);
  }
  bf16x8 a[16];
  {
    const bf16_t* ap = xb + (rb + wr * 32 + (l & 31)) * 256 + (l >> 5) * 8;
#pragma unroll
    for (int ks = 0; ks < 16; ++ks) a[ks] = *reinterpret_cast<const bf16x8*>(ap + ks * 16);
  }
  __syncthreads();
  float scale = 20.f / mean_norm[0];
  int hi = l >> 5;
#pragma unroll
  for (int cf = 0; cf < 2; ++cf) {
    f32x16 acc = {0.f,0.f,0.f,0.f,0.f,0.f,0.f,0.f,0.f,0.f,0.f,0.f,0.f,0.f,0.f,0.f};
#pragma unroll
    for (int ks = 0; ks < 16; ++ks) {
      bf16x8 b = *reinterpret_cast<const bf16x8*>(bs + ((wc * 2 + cf) * 16 + ks) * 512 + l * 8);
      acc = __builtin_amdgcn_mfma_f32_32x32x16_bf16(a[ks], b, acc, 0, 0, 0);
    }
    int col = cbase + wc * 64 + cf * 32 + (l & 31);
    int q = col >> 8, d = col & 255;
    float bias = conv_b[d], mn = mean[d];
    int qi = q >> 1, qj = q & 1;
#pragma unroll
    for (int r = 0; r < 16; ++r) {
      int p3 = rb + wr * 32 + (r & 3) + 8 * (r >> 2) + 4 * hi;
      int n = p3 / PIX, hw = p3 % PIX;
      int h = hw / 14, ww = hw % 14;
      int p = n * 784 + (2 * h + qi) * 28 + 2 * ww + qj;
      float v = fmaxf(acc[r] + bias, 0.f);
      fb[p * 256 + d] = (bf16_t)((v - mn) * scale);
    }
  }
}

// ---- e_f[p] = exp(-||f_p||^2/(2s^2)) from rounded bf16 ----
__global__ __launch_bounds__(256) void k_ef(const bf16_t* __restrict__ fb,
                                            const float* __restrict__ sigma,
                                            float* __restrict__ e_f) {
  int lane = threadIdx.x & 63;
  int row = blockIdx.x * 4 + (threadIdx.x >> 6);   // < 12544
  bf16x4 h = *reinterpret_cast<const bf16x4*>(fb + row * 256 + lane * 4);
  float sq = 0.f;
#pragma unroll
  for (int i = 0; i < 4; ++i) {
    float fv = (float)h[i];
    sq += fv * fv;
  }
#pragma unroll
  for (int o = 1; o < 64; o <<= 1) sq += __shfl_xor(sq, o);
  if (lane == 0) {
    float s = sigma[0];
    e_f[row] = __expf(-sq / (2.f * s * s));
  }
}

// ---- background channel = -2 ----
__global__ __launch_bounds__(256) void k_fill(float* __restrict__ out) {
  int idx = blockIdx.x * 256 + threadIdx.x;   // < 12544
  int n = idx / 784, pix = idx % 784;
  out[n * 16464 + pix] = -2.0f;
}

// ---- main: scores[c,p] = e_f[p] * sum_m e_n[m] * exp(dot/s^2) ----
// grid (49, 20); 4 waves x 64 p-rows; 32x32x16 MFMA; B double-buffered in LDS
// via global_load_lds; e_n in LDS; 2-phase sync per 32-m chunk.
__global__ __launch_bounds__(256, 2) void k_falkon(const bf16_t* __restrict__ fb,
                                                   const float* __restrict__ e_f,
                                                   const bf16_t* __restrict__ nys,
                                                   const float* __restrict__ e_n,
                                                   const float* __restrict__ sigma,
                                                   float* __restrict__ out) {
  __shared__ bf16_t bs[2][8192];   // 2 x 16 KB chunks
  __shared__ float lds_en[512];
  int c = blockIdx.y, pb = blockIdx.x * 256;
  int tid = threadIdx.x, w = tid >> 6, l = tid & 63;

  lds_en[tid] = e_n[c * M_ + tid];
  lds_en[256 + tid] = e_n[c * M_ + 256 + tid];

  // A frags: wave w rows pb + w*64 + fr*32 + (l&31); k = ks*16 + (l>>5)*8 + j
  bf16x8 a[2][16];
#pragma unroll
  for (int fr = 0; fr < 2; ++fr) {
    const bf16_t* ap = fb + (pb + w * 64 + fr * 32 + (l & 31)) * 256 + (l >> 5) * 8;
#pragma unroll
    for (int ks = 0; ks < 16; ++ks) a[fr][ks] = *reinterpret_cast<const bf16x8*>(ap + ks * 16);
  }

  float s = sigma[0];
  float kk = 1.f / (s * s);
  f32x16 sacc0 = {0.f,0.f,0.f,0.f,0.f,0.f,0.f,0.f,0.f,0.f,0.f,0.f,0.f,0.f,0.f,0.f};
  f32x16 sacc1 = {0.f,0.f,0.f,0.f,0.f,0.f,0.f,0.f,0.f,0.f,0.f,0.f,0.f,0.f,0.f,0.f};

  const bf16_t* nb = nys + c * (16 * 8192);

  // prologue: stage chunk 0 into bs[0]  (1024 slots of 16B, 256 threads x 4)
#pragma unroll
  for (int r = 0; r < 4; ++r) {
    int slot = (r * 4 + w) * 64 + l;
    gload_lds16(nb + slot * 8, &bs[0][slot * 8]);
  }
  __syncthreads();

  int cur = 0;
  for (int t = 0; t < 16; ++t) {
    if (t + 1 < 16) {
      const bf16_t* src = nb + (t + 1) * 8192;
#pragma unroll
      for (int r = 0; r < 4; ++r) {
        int slot = (r * 4 + w) * 64 + l;
        gload_lds16(src + slot * 8, &bs[cur ^ 1][slot * 8]);
      }
    }
    f32x16 acc0 = {0.f,0.f,0.f,0.f,0.f,0.f,0.f,0.f,0.f,0.f,0.f,0.f,0.f,0.f,0.f,0.f};
    f32x16 acc1 = {0.f,0.f,0.f,0.f,0.f,0.f,0.f,0.f,0.f,0.f,0.f,0.f,0.f,0.f,0.f,0.f};
    const bf16_t* bp = &bs[cur][0];
#pragma unroll
    for (int ks = 0; ks < 16; ++ks) {
      bf16x8 b = *reinterpret_cast<const bf16x8*>(bp + ks * 512 + l * 8);
      acc0 = __builtin_amdgcn_mfma_f32_32x32x16_bf16(a[0][ks], b, acc0, 0, 0, 0);
      acc1 = __builtin_amdgcn_mfma_f32_32x32x16_bf16(a[1][ks], b, acc1, 0, 0, 0);
    }
    float en = lds_en[t * 32 + (l & 31)];
#pragma unroll
    for (int r = 0; r < 16; ++r) {
      sacc0[r] += en * __expf(acc0[r] * kk);
      sacc1[r] += en * __expf(acc1[r] * kk);
    }
    __syncthreads();
    cur ^= 1;
  }

  // reduce over 32 m-lanes within each half-wave; lanes 0 and 32 write
#pragma unroll
  for (int fr = 0; fr < 2; ++fr) {
#pragma unroll
    for (int r = 0; r < 16; ++r) {
      float v = (fr == 0) ? sacc0[r] : sacc1[r];
      v += __shfl_xor(v, 1);
      v += __shfl_xor(v, 2);
      v += __shfl_xor(v, 4);
      v += __shfl_xor(v, 8);
      v += __shfl_xor(v, 16);
      if ((l & 31) == 0) {
        int p = pb + w * 64 + fr * 32 + (r & 3) + 8 * (r >> 2) + 4 * (l >> 5);
        float score = v * e_f[p];
        int n = p / 784, pix = p % 784;
        out[n * 16464 + (c + 1) * 784 + pix] = score;
      }
    }
  }
}

extern "C" void kernel_launch(void* const* d_in, const int* in_sizes, int n_in,
                              void* d_out, int out_size, void* d_ws, size_t ws_size,
                              hipStream_t stream) {
  const float* x         = (const float*)d_in[0];
  const float* conv_w    = (const float*)d_in[1];
  const float* conv_b    = (const float*)d_in[2];
  const float* mean      = (const float*)d_in[3];
  const float* mean_norm = (const float*)d_in[4];
  const float* ny        = (const float*)d_in[5];
  const float* alpha     = (const float*)d_in[6];
  const float* sigma     = (const float*)d_in[7];
  float* out = (float*)d_out;

  char* ws = (char*)d_ws;
  bf16_t* wtb = (bf16_t*)ws;                    //   524,288 B
  bf16_t* xb  = (bf16_t*)(ws + 524288);         // 1,605,632 B
  bf16_t* fb  = (bf16_t*)(ws + 2129920);        // 6,422,528 B
  float*  e_f = (float*)(ws + 8552448);         //    50,176 B
  bf16_t* nys = (bf16_t*)(ws + 8602624);        // 5,242,880 B
  float*  e_n = (float*)(ws + 13845504);        //    40,960 B

  k_wtb<<<dim3(256), dim3(256), 0, stream>>>(conv_w, wtb);
  k_xt<<<dim3(16, 4), dim3(256), 0, stream>>>(x, xb);
  k_nyprep<<<dim3(2560), dim3(256), 0, stream>>>(ny, alpha, sigma, nys, e_n);
  k_convT<<<dim3(49, 8), dim3(256), 0, stream>>>(xb, wtb, conv_b, mean, mean_norm, fb);
  k_ef<<<dim3(3136), dim3(256), 0, stream>>>(fb, sigma, e_f);
  k_fill<<<dim3(49), dim3(256), 0, stream>>>(out);
  k_falkon<<<dim3(49, 20), dim3(256), 0, stream>>>(fb, e_f, nys, e_n, sigma, out);
}